// Round 6
// baseline (615.536 us; speedup 1.0000x reference)
//
#include <hip/hip_runtime.h>
#include <hip/hip_bf16.h>

namespace {
constexpr int NB = 2, NS = 2048, NH = 16, ND = 128;
constexpr int QB = 64, KB = 64;
constexpr int NQT = NS / QB;            // 32 q-tiles
constexpr int ROWSTRIDE = NH * ND;      // 2048 floats between seq positions
constexpr float SCALE_LOG2E = 0.08838834764831843f * 1.4426950408889634f;

constexpr int K_OFF = 0;       // K tile  [64][128] bf16, 256B rows, swz ((r&7)<<4)
constexpr int V_OFF = 16384;   // Vt tile [128 d][64 k] bf16, 128B rows, swz (((d>>1)&7)<<4)
constexpr int P_OFF = 32768;   // per-wave P [16][64] bf16, 128B rows, swz ((q&7)<<4)
constexpr int P_WSZ = 2048;
constexpr int SMEM_SZ = P_OFF + 4 * P_WSZ;  // 40960 B -> exactly 4 blocks/CU
}

typedef __attribute__((ext_vector_type(4))) float f32x4;
typedef __attribute__((ext_vector_type(8))) short bf16x8;
typedef __attribute__((ext_vector_type(2))) unsigned int u32x2;

__device__ __forceinline__ unsigned short f2bf(float f) {
  union { __hip_bfloat16 h; unsigned short u; } cv;
  cv.h = __float2bfloat16(f);
  return cv.u;
}

__device__ __forceinline__ float bcast_row(const float v[4], int lane) {
  int q = lane & 15;
  int src = ((q >> 2) << 4) | q;
  float a0 = __shfl(v[0], src, 64);
  float a1 = __shfl(v[1], src, 64);
  float a2 = __shfl(v[2], src, 64);
  float a3 = __shfl(v[3], src, 64);
  int r = q & 3;
  return (r == 0) ? a0 : ((r == 1) ? a1 : ((r == 2) ? a2 : a3));
}

__global__ __launch_bounds__(256, 4)
void fattn_fwd(const float* __restrict__ Q, const float* __restrict__ K,
               const float* __restrict__ V, float* __restrict__ O) {
  __shared__ __align__(16) char smem[SMEM_SZ];

  // Decode: XCD = bid&7 (hw round-robin). Each XCD owns 4 (b,h) slices for L2
  // K/V locality (round-5: FETCH 520->49 MB). Within an XCD, qt DESCENDING
  // (LPT): heavy q-tiles dispatched first, 1-iter tiles last -> tiny tail.
  const int bid = blockIdx.x;
  const int x = bid & 7;          // XCD
  const int j = bid >> 3;         // 0..127 within XCD, dispatch order
  const int qt = (NQT - 1) - (j >> 2);
  const int hb = x + 8 * (j & 3); // 4 (h,b) combos per XCD
  const int h = hb >> 1;
  const int b = hb & 1;

  const int t = threadIdx.x;
  const int w = t >> 6;
  const int lane = t & 63;
  const int g = lane >> 4;
  const int cc = lane & 15;

  const size_t bh = ((size_t)b * NS * NH + h) * (size_t)ND;

  char* Kl = smem + K_OFF;
  char* Vl = smem + V_OFF;
  char* Pl = smem + P_OFF + w * P_WSZ;

  const int kc4 = t & 31;          // staging: float4 column chunk
  const int kr = t >> 5;           // staging: K row base
  const int vr0a = (t >> 5) * 4;   // staging: V 4-row group A
  const int vr0b = vr0a + 32;      // staging: V 4-row group B

  // ---- Q fragments in registers: A[row=cc][d = dc*32 + 8g + i] ----
  bf16x8 qf[4];
  {
    const float* qp = Q + bh + (size_t)(qt * QB + w * 16 + cc) * ROWSTRIDE;
#pragma unroll
    for (int dc = 0; dc < 4; ++dc) {
      f32x4 v0 = *reinterpret_cast<const f32x4*>(qp + dc * 32 + 8 * g);
      f32x4 v1 = *reinterpret_cast<const f32x4*>(qp + dc * 32 + 8 * g + 4);
      bf16x8 f;
      f[0] = (short)f2bf(v0[0]); f[1] = (short)f2bf(v0[1]);
      f[2] = (short)f2bf(v0[2]); f[3] = (short)f2bf(v0[3]);
      f[4] = (short)f2bf(v1[0]); f[5] = (short)f2bf(v1[1]);
      f[6] = (short)f2bf(v1[2]); f[7] = (short)f2bf(v1[3]);
      qf[dc] = f;
    }
  }

  f32x4 oacc[8];  // O^T accumulator: row d = mt*16+4g+reg, col q = cc
#pragma unroll
  for (int i = 0; i < 8; ++i) { oacc[i][0] = 0.f; oacc[i][1] = 0.f; oacc[i][2] = 0.f; oacc[i][3] = 0.f; }
  float m_run[4] = {-1e30f, -1e30f, -1e30f, -1e30f};
  float l_run[4] = {0.f, 0.f, 0.f, 0.f};

  for (int kt = 0; kt <= qt; ++kt) {
    const int kb = kt * KB;
    const bool diag = (kt == qt);

    // ---- stage K tile: loads first (MLP), then convert+swizzled LDS write ----
    {
      f32x4 kreg[8];
#pragma unroll
      for (int jj = 0; jj < 8; ++jj)
        kreg[jj] = *reinterpret_cast<const f32x4*>(
            K + bh + (size_t)(kb + kr + jj * 8) * ROWSTRIDE + kc4 * 4);
#pragma unroll
      for (int jj = 0; jj < 8; ++jj) {
        int r = kr + jj * 8;
        unsigned int klo = (unsigned int)f2bf(kreg[jj][0]) | ((unsigned int)f2bf(kreg[jj][1]) << 16);
        unsigned int khi = (unsigned int)f2bf(kreg[jj][2]) | ((unsigned int)f2bf(kreg[jj][3]) << 16);
        int kbyte = (r * 256 + kc4 * 8) ^ ((r & 7) << 4);
        u32x2 kk; kk[0] = klo; kk[1] = khi;
        *reinterpret_cast<u32x2*>(Kl + kbyte) = kk;
      }
    }
    // ---- stage V transposed: 4x4 register transpose, b64 swizzled writes ----
    {
      f32x4 vreg[2][4];
#pragma unroll
      for (int it = 0; it < 2; ++it) {
        int r0 = it ? vr0b : vr0a;
        const float* vp = V + bh + (size_t)(kb + r0) * ROWSTRIDE + kc4 * 4;
#pragma unroll
        for (int jv = 0; jv < 4; ++jv)
          vreg[it][jv] = *reinterpret_cast<const f32x4*>(vp + (size_t)jv * ROWSTRIDE);
      }
#pragma unroll
      for (int it = 0; it < 2; ++it) {
        int r0 = it ? vr0b : vr0a;
#pragma unroll
        for (int jv = 0; jv < 4; ++jv) {
          int d = 4 * kc4 + jv;
          unsigned int lo = (unsigned int)f2bf(vreg[it][0][jv]) | ((unsigned int)f2bf(vreg[it][1][jv]) << 16);
          unsigned int hi = (unsigned int)f2bf(vreg[it][2][jv]) | ((unsigned int)f2bf(vreg[it][3][jv]) << 16);
          int vbyte = (d * 128 + r0 * 2) ^ (((d >> 1) & 7) << 4);
          u32x2 pk; pk[0] = lo; pk[1] = hi;
          *reinterpret_cast<u32x2*>(Vl + vbyte) = pk;
        }
      }
    }
    __syncthreads();

    // ---- S = Q K^T (diag: skip fully-masked nt > w sub-tiles; wave-uniform) ----
    f32x4 s[4];
    __builtin_amdgcn_s_setprio(1);
#pragma unroll
    for (int nt = 0; nt < 4; ++nt) {
      const bool active = !diag || (nt <= w);
      if (active) {
        f32x4 acc; acc[0] = 0.f; acc[1] = 0.f; acc[2] = 0.f; acc[3] = 0.f;
        int row = nt * 16 + cc;
#pragma unroll
        for (int dc = 0; dc < 4; ++dc) {
          int byte = (row * 256 + dc * 64 + g * 16) ^ ((row & 7) << 4);
          bf16x8 kf = *reinterpret_cast<const bf16x8*>(Kl + byte);
          acc = __builtin_amdgcn_mfma_f32_16x16x32_bf16(qf[dc], kf, acc, 0, 0, 0);
        }
        s[nt] = acc;
      } else {
        s[nt][0] = -1e30f; s[nt][1] = -1e30f; s[nt][2] = -1e30f; s[nt][3] = -1e30f;
      }
    }
    __builtin_amdgcn_s_setprio(0);

    // ---- causal mask on diagonal sub-tile nt == w (others fully kept/skipped) ----
    if (diag) {
#pragma unroll
      for (int r = 0; r < 4; ++r)
        if (cc > g * 4 + r) s[w][r] = -1e30f;
    }

    // ---- online softmax (row q = 4g+reg; reduce across 16 lanes of quad-group) ----
    float tmax[4];
#pragma unroll
    for (int r = 0; r < 4; ++r)
      tmax[r] = fmaxf(fmaxf(s[0][r], s[1][r]), fmaxf(s[2][r], s[3][r]));
#pragma unroll
    for (int off = 1; off < 16; off <<= 1) {
#pragma unroll
      for (int r = 0; r < 4; ++r)
        tmax[r] = fmaxf(tmax[r], __shfl_xor(tmax[r], off, 64));
    }
    float alpha[4];
#pragma unroll
    for (int r = 0; r < 4; ++r) {
      float mn = fmaxf(m_run[r], tmax[r]);
      alpha[r] = exp2f((m_run[r] - mn) * SCALE_LOG2E);
      m_run[r] = mn;
    }
    float p[4][4];
    float psum[4] = {0.f, 0.f, 0.f, 0.f};
#pragma unroll
    for (int nt = 0; nt < 4; ++nt)
#pragma unroll
      for (int r = 0; r < 4; ++r) {
        float pv = exp2f((s[nt][r] - m_run[r]) * SCALE_LOG2E);
        p[nt][r] = pv;
        psum[r] += pv;
      }
#pragma unroll
    for (int r = 0; r < 4; ++r) l_run[r] = l_run[r] * alpha[r] + psum[r];

    float aq = bcast_row(alpha, lane);
#pragma unroll
    for (int mt = 0; mt < 8; ++mt) {
      oacc[mt][0] *= aq; oacc[mt][1] *= aq; oacc[mt][2] *= aq; oacc[mt][3] *= aq;
    }

    // ---- write P tile (bf16) to wave-private LDS [16][64], swizzled rows ----
#pragma unroll
    for (int nt = 0; nt < 4; ++nt)
#pragma unroll
      for (int r = 0; r < 4; ++r) {
        int pbyte = ((g * 4 + r) * 128 + (nt * 16 + cc) * 2) ^ (((g * 4 + r) & 7) << 4);
        *reinterpret_cast<unsigned short*>(Pl + pbyte) = f2bf(p[nt][r]);
      }

    asm volatile("s_waitcnt lgkmcnt(0)" ::: "memory");
    __builtin_amdgcn_sched_barrier(0);

    // ---- O^T += Vt * P^T (diag: skip kc=1 for waves 0,1 — fully-masked half) ----
    __builtin_amdgcn_s_setprio(1);
#pragma unroll
    for (int kc = 0; kc < 2; ++kc) {
      const bool active = !diag || (kc * 32 <= w * 16 + 15);
      if (active) {
        int pbyte = (cc * 128 + kc * 64 + g * 16) ^ ((cc & 7) << 4);
        bf16x8 pf = *reinterpret_cast<const bf16x8*>(Pl + pbyte);
#pragma unroll
        for (int mt = 0; mt < 8; ++mt) {
          int d = mt * 16 + cc;
          int byte = (d * 128 + kc * 64 + g * 16) ^ (((d >> 1) & 7) << 4);
          bf16x8 vf = *reinterpret_cast<const bf16x8*>(Vl + byte);
          oacc[mt] = __builtin_amdgcn_mfma_f32_16x16x32_bf16(vf, pf, oacc[mt], 0, 0, 0);
        }
      }
    }
    __builtin_amdgcn_s_setprio(0);
    __syncthreads();
  }

  // ---- epilogue: finish row sums, normalize, store ----
#pragma unroll
  for (int off = 1; off < 16; off <<= 1) {
#pragma unroll
    for (int r = 0; r < 4; ++r)
      l_run[r] += __shfl_xor(l_run[r], off, 64);
  }
  float Lq = bcast_row(l_run, lane);
  float inv = 1.0f / Lq;

  float* op = O + bh + (size_t)(qt * QB + w * 16 + cc) * ROWSTRIDE;
#pragma unroll
  for (int mt = 0; mt < 8; ++mt)
#pragma unroll
    for (int r = 0; r < 4; ++r)
      op[mt * 16 + g * 4 + r] = oacc[mt][r] * inv;
}

extern "C" void kernel_launch(void* const* d_in, const int* in_sizes, int n_in,
                              void* d_out, int out_size, void* d_ws, size_t ws_size,
                              hipStream_t stream) {
  const float* Q = (const float*)d_in[0];
  const float* K = (const float*)d_in[1];
  const float* V = (const float*)d_in[2];
  float* O = (float*)d_out;
  dim3 grid(NQT * NH * NB);   // 1024 blocks, 1D; XCD+LPT decode in-kernel
  fattn_fwd<<<grid, dim3(256), 0, stream>>>(Q, K, V, O);
}

// Round 7
// 575.510 us; speedup vs baseline: 1.0695x; 1.0695x over previous
//
#include <hip/hip_runtime.h>
#include <hip/hip_bf16.h>

namespace {
constexpr int NB = 2, NS = 2048, NH = 16, ND = 128;
constexpr int QB = 64, KB = 64;
constexpr int NQT = NS / QB;            // 32 q-tiles
constexpr int ROWSTRIDE = NH * ND;      // 2048 floats between seq positions
constexpr float SCALE_LOG2E = 0.08838834764831843f * 1.4426950408889634f;

constexpr int K_OFF = 0;       // K tile  [64][128] bf16, 256B rows, swz ((r&7)<<4)
constexpr int V_OFF = 16384;   // Vt tile [128 d][64 k] bf16, 128B rows, swz (((d>>1)&7)<<4)
constexpr int P_OFF = 32768;   // per-wave P [16][64] bf16, 128B rows, swz ((q&7)<<4)
constexpr int P_WSZ = 2048;
constexpr int SMEM_SZ = P_OFF + 4 * P_WSZ;  // 40960 B -> exactly 4 blocks/CU
}

typedef __attribute__((ext_vector_type(4))) float f32x4;
typedef __attribute__((ext_vector_type(8))) short bf16x8;
typedef __attribute__((ext_vector_type(2))) unsigned int u32x2;

__device__ __forceinline__ unsigned short f2bf(float f) {
  union { __hip_bfloat16 h; unsigned short u; } cv;
  cv.h = __float2bfloat16(f);
  return cv.u;
}

__device__ __forceinline__ float bcast_row(const float v[4], int lane) {
  int q = lane & 15;
  int src = ((q >> 2) << 4) | q;
  float a0 = __shfl(v[0], src, 64);
  float a1 = __shfl(v[1], src, 64);
  float a2 = __shfl(v[2], src, 64);
  float a3 = __shfl(v[3], src, 64);
  int r = q & 3;
  return (r == 0) ? a0 : ((r == 1) ? a1 : ((r == 2) ? a2 : a3));
}

__global__ __launch_bounds__(256, 4)
void fattn_fwd(const float* __restrict__ Q, const float* __restrict__ K,
               const float* __restrict__ V, float* __restrict__ O) {
  __shared__ __align__(16) char smem[SMEM_SZ];

  // Decode: XCD = bid&7 (hw round-robin). Each XCD owns 4 (b,h) slices for L2
  // K/V locality (round-5: FETCH 520->49 MB). Within an XCD, qt DESCENDING
  // (LPT): heavy q-tiles dispatched first, 1-iter tiles last -> tiny tail.
  const int bid = blockIdx.x;
  const int x = bid & 7;          // XCD
  const int j = bid >> 3;         // 0..127 within XCD, dispatch order
  const int qt = (NQT - 1) - (j >> 2);
  const int hb = x + 8 * (j & 3); // 4 (h,b) combos per XCD
  const int h = hb >> 1;
  const int b = hb & 1;

  const int t = threadIdx.x;
  const int w = t >> 6;
  const int lane = t & 63;
  const int g = lane >> 4;
  const int cc = lane & 15;

  const size_t bh = ((size_t)b * NS * NH + h) * (size_t)ND;

  char* Kl = smem + K_OFF;
  char* Vl = smem + V_OFF;
  char* Pl = smem + P_OFF + w * P_WSZ;

  const int kc4 = t & 31;          // staging: float4 column chunk
  const int kr = t >> 5;           // staging: K row base
  const int vr0a = (t >> 5) * 4;   // staging: V 4-row group A
  const int vr0b = vr0a + 32;      // staging: V 4-row group B

  // ---- Q fragments in registers: A[row=cc][d = dc*32 + 8g + i] ----
  bf16x8 qf[4];
  {
    const float* qp = Q + bh + (size_t)(qt * QB + w * 16 + cc) * ROWSTRIDE;
#pragma unroll
    for (int dc = 0; dc < 4; ++dc) {
      f32x4 v0 = *reinterpret_cast<const f32x4*>(qp + dc * 32 + 8 * g);
      f32x4 v1 = *reinterpret_cast<const f32x4*>(qp + dc * 32 + 8 * g + 4);
      bf16x8 f;
      f[0] = (short)f2bf(v0[0]); f[1] = (short)f2bf(v0[1]);
      f[2] = (short)f2bf(v0[2]); f[3] = (short)f2bf(v0[3]);
      f[4] = (short)f2bf(v1[0]); f[5] = (short)f2bf(v1[1]);
      f[6] = (short)f2bf(v1[2]); f[7] = (short)f2bf(v1[3]);
      qf[dc] = f;
    }
  }

  f32x4 oacc[8];  // O^T accumulator: row d = mt*16+4g+reg, col q = cc
#pragma unroll
  for (int i = 0; i < 8; ++i) { oacc[i][0] = 0.f; oacc[i][1] = 0.f; oacc[i][2] = 0.f; oacc[i][3] = 0.f; }
  float m_run[4] = {-1e30f, -1e30f, -1e30f, -1e30f};
  float l_run[4] = {0.f, 0.f, 0.f, 0.f};

  for (int kt = 0; kt <= qt; ++kt) {
    const int kb = kt * KB;
    const bool diag = (kt == qt);

    // ---- stage K tile: loads first (MLP), then convert+swizzled LDS write ----
    {
      f32x4 kreg[8];
#pragma unroll
      for (int jj = 0; jj < 8; ++jj)
        kreg[jj] = *reinterpret_cast<const f32x4*>(
            K + bh + (size_t)(kb + kr + jj * 8) * ROWSTRIDE + kc4 * 4);
#pragma unroll
      for (int jj = 0; jj < 8; ++jj) {
        int r = kr + jj * 8;
        unsigned int klo = (unsigned int)f2bf(kreg[jj][0]) | ((unsigned int)f2bf(kreg[jj][1]) << 16);
        unsigned int khi = (unsigned int)f2bf(kreg[jj][2]) | ((unsigned int)f2bf(kreg[jj][3]) << 16);
        int kbyte = (r * 256 + kc4 * 8) ^ ((r & 7) << 4);
        u32x2 kk; kk[0] = klo; kk[1] = khi;
        *reinterpret_cast<u32x2*>(Kl + kbyte) = kk;
      }
    }
    // ---- stage V transposed: 4x4 register transpose, b64 swizzled writes ----
    {
      f32x4 vreg[2][4];
#pragma unroll
      for (int it = 0; it < 2; ++it) {
        int r0 = it ? vr0b : vr0a;
        const float* vp = V + bh + (size_t)(kb + r0) * ROWSTRIDE + kc4 * 4;
#pragma unroll
        for (int jv = 0; jv < 4; ++jv)
          vreg[it][jv] = *reinterpret_cast<const f32x4*>(vp + (size_t)jv * ROWSTRIDE);
      }
#pragma unroll
      for (int it = 0; it < 2; ++it) {
        int r0 = it ? vr0b : vr0a;
#pragma unroll
        for (int jv = 0; jv < 4; ++jv) {
          int d = 4 * kc4 + jv;
          unsigned int lo = (unsigned int)f2bf(vreg[it][0][jv]) | ((unsigned int)f2bf(vreg[it][1][jv]) << 16);
          unsigned int hi = (unsigned int)f2bf(vreg[it][2][jv]) | ((unsigned int)f2bf(vreg[it][3][jv]) << 16);
          int vbyte = (d * 128 + r0 * 2) ^ (((d >> 1) & 7) << 4);
          u32x2 pk; pk[0] = lo; pk[1] = hi;
          *reinterpret_cast<u32x2*>(Vl + vbyte) = pk;
        }
      }
    }
    __syncthreads();

    // ---- S = Q K^T (diag: skip fully-masked nt > w sub-tiles; wave-uniform) ----
    f32x4 s[4];
    __builtin_amdgcn_s_setprio(1);
#pragma unroll
    for (int nt = 0; nt < 4; ++nt) {
      const bool active = !diag || (nt <= w);
      if (active) {
        f32x4 acc; acc[0] = 0.f; acc[1] = 0.f; acc[2] = 0.f; acc[3] = 0.f;
        int row = nt * 16 + cc;
#pragma unroll
        for (int dc = 0; dc < 4; ++dc) {
          int byte = (row * 256 + dc * 64 + g * 16) ^ ((row & 7) << 4);
          bf16x8 kf = *reinterpret_cast<const bf16x8*>(Kl + byte);
          acc = __builtin_amdgcn_mfma_f32_16x16x32_bf16(qf[dc], kf, acc, 0, 0, 0);
        }
        s[nt] = acc;
      } else {
        s[nt][0] = -1e30f; s[nt][1] = -1e30f; s[nt][2] = -1e30f; s[nt][3] = -1e30f;
      }
    }
    __builtin_amdgcn_s_setprio(0);

    // ---- causal mask on diagonal sub-tile nt == w; STATIC indexing only
    //      (rule #20: s[w][r] with runtime w demotes s[] to scratch — round-6 bug) ----
    if (diag) {
#pragma unroll
      for (int nt = 0; nt < 4; ++nt) {
        if (nt == w) {   // uniform predicate, compile-time index
#pragma unroll
          for (int r = 0; r < 4; ++r)
            if (cc > g * 4 + r) s[nt][r] = -1e30f;
        }
      }
    }

    // ---- online softmax (row q = 4g+reg; reduce across 16 lanes of quad-group) ----
    float tmax[4];
#pragma unroll
    for (int r = 0; r < 4; ++r)
      tmax[r] = fmaxf(fmaxf(s[0][r], s[1][r]), fmaxf(s[2][r], s[3][r]));
#pragma unroll
    for (int off = 1; off < 16; off <<= 1) {
#pragma unroll
      for (int r = 0; r < 4; ++r)
        tmax[r] = fmaxf(tmax[r], __shfl_xor(tmax[r], off, 64));
    }
    float alpha[4];
#pragma unroll
    for (int r = 0; r < 4; ++r) {
      float mn = fmaxf(m_run[r], tmax[r]);
      alpha[r] = exp2f((m_run[r] - mn) * SCALE_LOG2E);
      m_run[r] = mn;
    }
    float p[4][4];
    float psum[4] = {0.f, 0.f, 0.f, 0.f};
#pragma unroll
    for (int nt = 0; nt < 4; ++nt)
#pragma unroll
      for (int r = 0; r < 4; ++r) {
        float pv = exp2f((s[nt][r] - m_run[r]) * SCALE_LOG2E);
        p[nt][r] = pv;
        psum[r] += pv;
      }
#pragma unroll
    for (int r = 0; r < 4; ++r) l_run[r] = l_run[r] * alpha[r] + psum[r];

    float aq = bcast_row(alpha, lane);
#pragma unroll
    for (int mt = 0; mt < 8; ++mt) {
      oacc[mt][0] *= aq; oacc[mt][1] *= aq; oacc[mt][2] *= aq; oacc[mt][3] *= aq;
    }

    // ---- write P tile (bf16) to wave-private LDS [16][64], swizzled rows ----
#pragma unroll
    for (int nt = 0; nt < 4; ++nt)
#pragma unroll
      for (int r = 0; r < 4; ++r) {
        int pbyte = ((g * 4 + r) * 128 + (nt * 16 + cc) * 2) ^ (((g * 4 + r) & 7) << 4);
        *reinterpret_cast<unsigned short*>(Pl + pbyte) = f2bf(p[nt][r]);
      }

    asm volatile("s_waitcnt lgkmcnt(0)" ::: "memory");
    __builtin_amdgcn_sched_barrier(0);

    // ---- O^T += Vt * P^T (diag: skip kc=1 for waves 0,1 — fully-masked half) ----
    __builtin_amdgcn_s_setprio(1);
#pragma unroll
    for (int kc = 0; kc < 2; ++kc) {
      const bool active = !diag || (kc == 0) || (w >= 2);
      if (active) {
        int pbyte = (cc * 128 + kc * 64 + g * 16) ^ ((cc & 7) << 4);
        bf16x8 pf = *reinterpret_cast<const bf16x8*>(Pl + pbyte);
#pragma unroll
        for (int mt = 0; mt < 8; ++mt) {
          int d = mt * 16 + cc;
          int byte = (d * 128 + kc * 64 + g * 16) ^ (((d >> 1) & 7) << 4);
          bf16x8 vf = *reinterpret_cast<const bf16x8*>(Vl + byte);
          oacc[mt] = __builtin_amdgcn_mfma_f32_16x16x32_bf16(vf, pf, oacc[mt], 0, 0, 0);
        }
      }
    }
    __builtin_amdgcn_s_setprio(0);
    __syncthreads();
  }

  // ---- epilogue: finish row sums, normalize, store ----
#pragma unroll
  for (int off = 1; off < 16; off <<= 1) {
#pragma unroll
    for (int r = 0; r < 4; ++r)
      l_run[r] += __shfl_xor(l_run[r], off, 64);
  }
  float Lq = bcast_row(l_run, lane);
  float inv = 1.0f / Lq;

  float* op = O + bh + (size_t)(qt * QB + w * 16 + cc) * ROWSTRIDE;
#pragma unroll
  for (int mt = 0; mt < 8; ++mt)
#pragma unroll
    for (int r = 0; r < 4; ++r)
      op[mt * 16 + g * 4 + r] = oacc[mt][r] * inv;
}

extern "C" void kernel_launch(void* const* d_in, const int* in_sizes, int n_in,
                              void* d_out, int out_size, void* d_ws, size_t ws_size,
                              hipStream_t stream) {
  const float* Q = (const float*)d_in[0];
  const float* K = (const float*)d_in[1];
  const float* V = (const float*)d_in[2];
  float* O = (float*)d_out;
  dim3 grid(NQT * NH * NB);   // 1024 blocks, 1D; XCD+LPT decode in-kernel
  fattn_fwd<<<grid, dim3(256), 0, stream>>>(Q, K, V, O);
}

// Round 13
// 236.639 us; speedup vs baseline: 2.6012x; 2.4320x over previous
//
#include <hip/hip_runtime.h>
#include <hip/hip_bf16.h>

namespace {
constexpr int NB = 2, NS = 2048, NH = 16, ND = 128;
constexpr int QB = 64, KB = 64;
constexpr int NQT = NS / QB;            // 32 q-tiles
constexpr int ROWSTRIDE = NH * ND;      // 2048 floats between seq positions
constexpr float SCALE_LOG2E = 0.08838834764831843f * 1.4426950408889634f;

constexpr int K_OFF = 0;       // K tile  [64][128] bf16, 256B rows, swz ((r&7)<<4)
constexpr int V_OFF = 16384;   // Vt tile [128 d][64 k] bf16, 128B rows, swz (((d>>1)&7)<<4)
constexpr int P_OFF = 32768;   // per-wave P [16][64] bf16, 128B rows, swz ((q&7)<<4)
constexpr int P_WSZ = 2048;
constexpr int SMEM_SZ = P_OFF + 4 * P_WSZ;  // 40960 B; 4 blocks/CU = exactly 160 KiB
}

typedef __attribute__((ext_vector_type(4))) float f32x4;
typedef __attribute__((ext_vector_type(8))) short bf16x8;
typedef __attribute__((ext_vector_type(2))) unsigned int u32x2;

__device__ __forceinline__ unsigned short f2bf(float f) {
  union { __hip_bfloat16 h; unsigned short u; } cv;
  cv.h = __float2bfloat16(f);
  return cv.u;
}

__device__ __forceinline__ float bcast_row(const float v[4], int lane) {
  int q = lane & 15;
  int src = ((q >> 2) << 4) | q;
  float a0 = __shfl(v[0], src, 64);
  float a1 = __shfl(v[1], src, 64);
  float a2 = __shfl(v[2], src, 64);
  float a3 = __shfl(v[3], src, 64);
  int r = q & 3;
  return (r == 0) ? a0 : ((r == 1) ? a1 : ((r == 2) ? a2 : a3));
}

// NOTE: plain __launch_bounds__(256). Round 6/7 lesson: (256,4) forces a
// 128-reg unified budget on a ~170-reg body -> ~70 MB scratch spill traffic
// (WRITE_SIZE 32->103 MB, VGPR_Count 64, 3x slowdown). Compiler-chosen
// allocation (~120, round 3) natively supports 4 waves/EU without spill.
__global__ __launch_bounds__(256)
void fattn_fwd(const float* __restrict__ Q, const float* __restrict__ K,
               const float* __restrict__ V, float* __restrict__ O) {
  __shared__ __align__(16) char smem[SMEM_SZ];

  // Decode: XCD = bid&7 (hw round-robin). Each XCD owns 4 (b,h) slices for L2
  // K/V locality (round-5: FETCH 520->49 MB). Within an XCD, qt DESCENDING
  // (LPT): heavy q-tiles dispatched first, 1-iter tiles last -> tiny tail.
  const int bid = blockIdx.x;
  const int x = bid & 7;          // XCD
  const int j = bid >> 3;         // 0..127 within XCD, dispatch order
  const int qt = (NQT - 1) - (j >> 2);
  const int hb = x + 8 * (j & 3); // 4 (h,b) combos per XCD
  const int h = hb >> 1;
  const int b = hb & 1;

  const int t = threadIdx.x;
  const int w = t >> 6;
  const int lane = t & 63;
  const int g = lane >> 4;
  const int cc = lane & 15;

  const size_t bh = ((size_t)b * NS * NH + h) * (size_t)ND;

  char* Kl = smem + K_OFF;
  char* Vl = smem + V_OFF;
  char* Pl = smem + P_OFF + w * P_WSZ;

  const int kc4 = t & 31;          // staging: float4 column chunk
  const int kr = t >> 5;           // staging: K row base
  const int vr0a = (t >> 5) * 4;   // staging: V 4-row group A
  const int vr0b = vr0a + 32;      // staging: V 4-row group B

  // ---- Q fragments in registers: A[row=cc][d = dc*32 + 8g + i] ----
  bf16x8 qf[4];
  {
    const float* qp = Q + bh + (size_t)(qt * QB + w * 16 + cc) * ROWSTRIDE;
#pragma unroll
    for (int dc = 0; dc < 4; ++dc) {
      f32x4 v0 = *reinterpret_cast<const f32x4*>(qp + dc * 32 + 8 * g);
      f32x4 v1 = *reinterpret_cast<const f32x4*>(qp + dc * 32 + 8 * g + 4);
      bf16x8 f;
      f[0] = (short)f2bf(v0[0]); f[1] = (short)f2bf(v0[1]);
      f[2] = (short)f2bf(v0[2]); f[3] = (short)f2bf(v0[3]);
      f[4] = (short)f2bf(v1[0]); f[5] = (short)f2bf(v1[1]);
      f[6] = (short)f2bf(v1[2]); f[7] = (short)f2bf(v1[3]);
      qf[dc] = f;
    }
  }

  f32x4 oacc[8];  // O^T accumulator: row d = mt*16+4g+reg, col q = cc
#pragma unroll
  for (int i = 0; i < 8; ++i) { oacc[i][0] = 0.f; oacc[i][1] = 0.f; oacc[i][2] = 0.f; oacc[i][3] = 0.f; }
  float m_run[4] = {-1e30f, -1e30f, -1e30f, -1e30f};
  float l_run[4] = {0.f, 0.f, 0.f, 0.f};

  for (int kt = 0; kt <= qt; ++kt) {
    const int kb = kt * KB;
    const bool diag = (kt == qt);

    // ---- stage K tile: loads first (MLP), then convert+swizzled LDS write ----
    {
      f32x4 kreg[8];
#pragma unroll
      for (int jj = 0; jj < 8; ++jj)
        kreg[jj] = *reinterpret_cast<const f32x4*>(
            K + bh + (size_t)(kb + kr + jj * 8) * ROWSTRIDE + kc4 * 4);
#pragma unroll
      for (int jj = 0; jj < 8; ++jj) {
        int r = kr + jj * 8;
        unsigned int klo = (unsigned int)f2bf(kreg[jj][0]) | ((unsigned int)f2bf(kreg[jj][1]) << 16);
        unsigned int khi = (unsigned int)f2bf(kreg[jj][2]) | ((unsigned int)f2bf(kreg[jj][3]) << 16);
        int kbyte = (r * 256 + kc4 * 8) ^ ((r & 7) << 4);
        u32x2 kk; kk[0] = klo; kk[1] = khi;
        *reinterpret_cast<u32x2*>(Kl + kbyte) = kk;
      }
    }
    // ---- stage V transposed: 4x4 register transpose, b64 swizzled writes ----
    {
      f32x4 vreg[2][4];
#pragma unroll
      for (int it = 0; it < 2; ++it) {
        int r0 = it ? vr0b : vr0a;
        const float* vp = V + bh + (size_t)(kb + r0) * ROWSTRIDE + kc4 * 4;
#pragma unroll
        for (int jv = 0; jv < 4; ++jv)
          vreg[it][jv] = *reinterpret_cast<const f32x4*>(vp + (size_t)jv * ROWSTRIDE);
      }
#pragma unroll
      for (int it = 0; it < 2; ++it) {
        int r0 = it ? vr0b : vr0a;
#pragma unroll
        for (int jv = 0; jv < 4; ++jv) {
          int d = 4 * kc4 + jv;
          unsigned int lo = (unsigned int)f2bf(vreg[it][0][jv]) | ((unsigned int)f2bf(vreg[it][1][jv]) << 16);
          unsigned int hi = (unsigned int)f2bf(vreg[it][2][jv]) | ((unsigned int)f2bf(vreg[it][3][jv]) << 16);
          int vbyte = (d * 128 + r0 * 2) ^ (((d >> 1) & 7) << 4);
          u32x2 pk; pk[0] = lo; pk[1] = hi;
          *reinterpret_cast<u32x2*>(Vl + vbyte) = pk;
        }
      }
    }
    __syncthreads();

    // ---- S = Q K^T (diag: skip fully-masked nt > w sub-tiles; wave-uniform) ----
    f32x4 s[4];
    __builtin_amdgcn_s_setprio(1);
#pragma unroll
    for (int nt = 0; nt < 4; ++nt) {
      const bool active = !diag || (nt <= w);
      if (active) {
        f32x4 acc; acc[0] = 0.f; acc[1] = 0.f; acc[2] = 0.f; acc[3] = 0.f;
        int row = nt * 16 + cc;
#pragma unroll
        for (int dc = 0; dc < 4; ++dc) {
          int byte = (row * 256 + dc * 64 + g * 16) ^ ((row & 7) << 4);
          bf16x8 kf = *reinterpret_cast<const bf16x8*>(Kl + byte);
          acc = __builtin_amdgcn_mfma_f32_16x16x32_bf16(qf[dc], kf, acc, 0, 0, 0);
        }
        s[nt] = acc;
      } else {
        s[nt][0] = -1e30f; s[nt][1] = -1e30f; s[nt][2] = -1e30f; s[nt][3] = -1e30f;
      }
    }
    __builtin_amdgcn_s_setprio(0);

    // ---- causal mask on diagonal sub-tile nt == w (static index; rule #20) ----
    if (diag) {
#pragma unroll
      for (int nt = 0; nt < 4; ++nt) {
        if (nt == w) {
#pragma unroll
          for (int r = 0; r < 4; ++r)
            if (cc > g * 4 + r) s[nt][r] = -1e30f;
        }
      }
    }

    // ---- online softmax (row q = 4g+reg; reduce across 16 lanes of quad-group) ----
    float tmax[4];
#pragma unroll
    for (int r = 0; r < 4; ++r)
      tmax[r] = fmaxf(fmaxf(s[0][r], s[1][r]), fmaxf(s[2][r], s[3][r]));
#pragma unroll
    for (int off = 1; off < 16; off <<= 1) {
#pragma unroll
      for (int r = 0; r < 4; ++r)
        tmax[r] = fmaxf(tmax[r], __shfl_xor(tmax[r], off, 64));
    }
    float alpha[4];
#pragma unroll
    for (int r = 0; r < 4; ++r) {
      float mn = fmaxf(m_run[r], tmax[r]);
      alpha[r] = exp2f((m_run[r] - mn) * SCALE_LOG2E);
      m_run[r] = mn;
    }
    // exp + P-write fused (no p[4][4] temp -> ~16 fewer live regs)
    float psum[4] = {0.f, 0.f, 0.f, 0.f};
#pragma unroll
    for (int nt = 0; nt < 4; ++nt)
#pragma unroll
      for (int r = 0; r < 4; ++r) {
        float pv = exp2f((s[nt][r] - m_run[r]) * SCALE_LOG2E);
        psum[r] += pv;
        int pbyte = ((g * 4 + r) * 128 + (nt * 16 + cc) * 2) ^ (((g * 4 + r) & 7) << 4);
        *reinterpret_cast<unsigned short*>(Pl + pbyte) = f2bf(pv);
      }
#pragma unroll
    for (int r = 0; r < 4; ++r) l_run[r] = l_run[r] * alpha[r] + psum[r];

    float aq = bcast_row(alpha, lane);
#pragma unroll
    for (int mt = 0; mt < 8; ++mt) {
      oacc[mt][0] *= aq; oacc[mt][1] *= aq; oacc[mt][2] *= aq; oacc[mt][3] *= aq;
    }

    // wave-local fence: P writes must land before fragment reads (wave-private buffer)
    asm volatile("s_waitcnt lgkmcnt(0)" ::: "memory");
    __builtin_amdgcn_sched_barrier(0);

    // ---- O^T += Vt * P^T (diag: skip kc=1 for waves 0,1 — fully-masked half) ----
    __builtin_amdgcn_s_setprio(1);
#pragma unroll
    for (int kc = 0; kc < 2; ++kc) {
      const bool active = !diag || (kc == 0) || (w >= 2);
      if (active) {
        int pbyte = (cc * 128 + kc * 64 + g * 16) ^ ((cc & 7) << 4);
        bf16x8 pf = *reinterpret_cast<const bf16x8*>(Pl + pbyte);
#pragma unroll
        for (int mt = 0; mt < 8; ++mt) {
          int d = mt * 16 + cc;
          int byte = (d * 128 + kc * 64 + g * 16) ^ (((d >> 1) & 7) << 4);
          bf16x8 vf = *reinterpret_cast<const bf16x8*>(Vl + byte);
          oacc[mt] = __builtin_amdgcn_mfma_f32_16x16x32_bf16(vf, pf, oacc[mt], 0, 0, 0);
        }
      }
    }
    __builtin_amdgcn_s_setprio(0);
    __syncthreads();
  }

  // ---- epilogue: finish row sums, normalize, store ----
#pragma unroll
  for (int off = 1; off < 16; off <<= 1) {
#pragma unroll
    for (int r = 0; r < 4; ++r)
      l_run[r] += __shfl_xor(l_run[r], off, 64);
  }
  float Lq = bcast_row(l_run, lane);
  float inv = 1.0f / Lq;

  float* op = O + bh + (size_t)(qt * QB + w * 16 + cc) * ROWSTRIDE;
#pragma unroll
  for (int mt = 0; mt < 8; ++mt)
#pragma unroll
    for (int r = 0; r < 4; ++r)
      op[mt * 16 + g * 4 + r] = oacc[mt][r] * inv;
}

extern "C" void kernel_launch(void* const* d_in, const int* in_sizes, int n_in,
                              void* d_out, int out_size, void* d_ws, size_t ws_size,
                              hipStream_t stream) {
  const float* Q = (const float*)d_in[0];
  const float* K = (const float*)d_in[1];
  const float* V = (const float*)d_in[2];
  float* O = (float*)d_out;
  dim3 grid(NQT * NH * NB);   // 1024 blocks, 1D; XCD+LPT decode in-kernel
  fattn_fwd<<<grid, dim3(256), 0, stream>>>(Q, K, V, O);
}